// Round 4
// baseline (639.848 us; speedup 1.0000x reference)
//
#include <hip/hip_runtime.h>
#include <hip/hip_bf16.h>
#include <math.h>

#define CH 128      // OUT_SIZE * HEADS
#define KIN 128     // IN_SIZE
#define BH 128      // histogram / coarse-scatter block count
#define FCAP 4096   // max edges per 64-node bucket handled in LDS (mean 2046, sd 45)

__device__ __forceinline__ unsigned short f2bf(float x) {
    __hip_bfloat16 h = __float2bfloat16(x);
    return *reinterpret_cast<unsigned short*>(&h);
}

// ---------------- K1: Zp16 = bf16(Z @ W^T + b)  -> [N, 128] ----------------
__global__ __launch_bounds__(128) void k_gemm(const float* __restrict__ Z,
                                              const float* __restrict__ W,
                                              const float* __restrict__ b,
                                              unsigned short* __restrict__ Zp16, int N)
{
    __shared__ float lZ[32][36];
    __shared__ float lW[32][132];
    const int tid = threadIdx.x;
    const int c_t = tid & 15;
    const int n_t = tid >> 4;
    const int c0 = c_t * 8;
    const int nb0 = blockIdx.x * 32;

    float4 accA[4], accB[4];
    const float4 bA = *(const float4*)(b + c0);
    const float4 bB = *(const float4*)(b + c0 + 4);
#pragma unroll
    for (int n = 0; n < 4; n++) { accA[n] = bA; accB[n] = bB; }

    for (int k0 = 0; k0 < KIN; k0 += 32) {
#pragma unroll
        for (int r = 0; r < 2; r++) {
            int idx = tid + r * 128;
            int n   = idx >> 3;
            int kk  = (idx & 7) * 4;
            int gn  = nb0 + n; if (gn >= N) gn = N - 1;
            float4 v = *(const float4*)(Z + (size_t)gn * KIN + k0 + kk);
            *(float4*)(&lZ[n][kk]) = v;
        }
#pragma unroll
        for (int r = 0; r < 8; r++) {
            int idx = tid + r * 128;
            int c   = idx >> 3;
            int kk  = (idx & 7) * 4;
            float4 v = *(const float4*)(W + (size_t)c * KIN + k0 + kk);
            lW[kk + 0][c] = v.x; lW[kk + 1][c] = v.y;
            lW[kk + 2][c] = v.z; lW[kk + 3][c] = v.w;
        }
        __syncthreads();
#pragma unroll
        for (int kk = 0; kk < 32; kk += 4) {
            float4 z[4];
#pragma unroll
            for (int n = 0; n < 4; n++) z[n] = *(float4*)(&lZ[n_t * 4 + n][kk]);
#pragma unroll
            for (int j = 0; j < 4; j++) {
                float4 wa = *(float4*)(&lW[kk + j][c0]);
                float4 wb = *(float4*)(&lW[kk + j][c0 + 4]);
#pragma unroll
                for (int n = 0; n < 4; n++) {
                    float zs = (j == 0) ? z[n].x : (j == 1) ? z[n].y : (j == 2) ? z[n].z : z[n].w;
                    accA[n].x += zs * wa.x; accA[n].y += zs * wa.y;
                    accA[n].z += zs * wa.z; accA[n].w += zs * wa.w;
                    accB[n].x += zs * wb.x; accB[n].y += zs * wb.y;
                    accB[n].z += zs * wb.z; accB[n].w += zs * wb.w;
                }
            }
        }
        __syncthreads();
    }
#pragma unroll
    for (int n = 0; n < 4; n++) {
        int gn = nb0 + n_t * 4 + n;
        if (gn < N) {
            union { unsigned short us[8]; uint4 v; } pk;
            pk.us[0] = f2bf(accA[n].x); pk.us[1] = f2bf(accA[n].y);
            pk.us[2] = f2bf(accA[n].z); pk.us[3] = f2bf(accA[n].w);
            pk.us[4] = f2bf(accB[n].x); pk.us[5] = f2bf(accB[n].y);
            pk.us[6] = f2bf(accB[n].z); pk.us[7] = f2bf(accB[n].w);
            *(uint4*)(Zp16 + (size_t)gn * CH + c0) = pk.v;
        }
    }
}

// ---------------- K1b: per-node attention logits (reads bf16 Zp) ----------------
__global__ __launch_bounds__(256) void k_logits(const unsigned short* __restrict__ Zp16,
                                                const float* __restrict__ al,
                                                const float* __restrict__ ar,
                                                float* __restrict__ el,
                                                float* __restrict__ er, int N)
{
    int wave = threadIdx.x >> 6;
    int lane = threadIdx.x & 63;
    int node = blockIdx.x * 4 + wave;
    if (node >= N) return;
    float z1 = __uint_as_float((unsigned)Zp16[(size_t)node * CH + lane] << 16);
    float z2 = __uint_as_float((unsigned)Zp16[(size_t)node * CH + 64 + lane] << 16);
    float vl = z1 * al[lane] + z2 * al[64 + lane];
    float vr = z1 * ar[lane] + z2 * ar[64 + lane];
#pragma unroll
    for (int m = 4; m <= 32; m <<= 1) {
        vl += __shfl_xor(vl, m, 64);
        vr += __shfl_xor(vr, m, 64);
    }
    if (lane < 4) {
        el[node * 4 + lane] = vl;
        er[node * 4 + lane] = vr;
    }
}

// ---------------- K2: per-block bucket histograms + bucket totals ----------------
// H layout: [side(2)][bucket(NBK)][block(BH)]; btot must be pre-zeroed
__global__ __launch_bounds__(256) void k_hist(const int* __restrict__ idx,
                                              int* __restrict__ H,
                                              int* __restrict__ btot, int E, int NBK)
{
    __shared__ int lc[2 * 1024];
    int b = blockIdx.x, t = threadIdx.x;
    for (int i = t; i < 2 * NBK; i += 256) lc[i] = 0;
    __syncthreads();
    int chunk = (E + BH - 1) / BH;
    int lo = b * chunk, hi = min(lo + chunk, E);
    for (int e = lo + t; e < hi; e += 256) {
        int s = idx[e], d = idx[E + e];
        atomicAdd(&lc[s >> 6], 1);
        atomicAdd(&lc[NBK + (d >> 6)], 1);
    }
    __syncthreads();
    for (int i = t; i < 2 * NBK; i += 256) {
        int v = lc[i];
        H[(size_t)i * BH + b] = v;
        if (v) atomicAdd(&btot[i], v);
    }
}

// ---------------- K3b: single-block exclusive scan (n <= ~2048) ----------------
__global__ __launch_bounds__(1024) void k_scan(const int* __restrict__ deg,
                                               int* __restrict__ offs, int n)
{
    __shared__ int part[1024];
    int t = threadIdx.x;
    int chunk = (n + 1023) >> 10;
    int lo = t * chunk;
    int hi = min(lo + chunk, n);
    int s = 0;
    for (int i = lo; i < hi; i++) s += deg[i];
    part[t] = s;
    __syncthreads();
    for (int off = 1; off < 1024; off <<= 1) {
        int v = (t >= off) ? part[t - off] : 0;
        __syncthreads();
        part[t] += v;
        __syncthreads();
    }
    int run = (t == 0) ? 0 : part[t - 1];
    for (int i = lo; i < hi; i++) { offs[i] = run; run += deg[i]; }
    if (t == 1023) offs[n] = part[1023];
}

// ---------------- K3c: per-bucket block bases ----------------
__global__ __launch_bounds__(128) void k_bbase(int* __restrict__ H,
                                               const int* __restrict__ bbase)
{
    int i = blockIdx.x, t = threadIdx.x;
    int v = H[(size_t)i * BH + t];
    __shared__ int part[128];
    part[t] = v;
    __syncthreads();
    for (int off = 1; off < 128; off <<= 1) {
        int u = (t >= off) ? part[t - off] : 0;
        __syncthreads();
        part[t] += u;
        __syncthreads();
    }
    H[(size_t)i * BH + t] = (t == 0 ? 0 : part[t - 1]) + bbase[i];
}

// ---------------- K4: coarse scatter into bucket-sorted array ----------------
// payload: (node&63)<<26 | other_node (other_node < 65536)
__global__ __launch_bounds__(256) void k_coarse(const int* __restrict__ idx,
                                                const int* __restrict__ H,
                                                unsigned* __restrict__ C,
                                                int E, int NBK)
{
    __shared__ int lc[2 * 1024];
    int b = blockIdx.x, t = threadIdx.x;
    for (int i = t; i < 2 * NBK; i += 256) lc[i] = H[(size_t)i * BH + b];
    __syncthreads();
    int chunk = (E + BH - 1) / BH;
    int lo = b * chunk, hi = min(lo + chunk, E);
    for (int e = lo + t; e < hi; e += 256) {
        int s = idx[e], d = idx[E + e];
        int p = atomicAdd(&lc[s >> 6], 1);
        C[p] = ((unsigned)(s & 63) << 26) | (unsigned)d;
        int p2 = atomicAdd(&lc[NBK + (d >> 6)], 1);
        C[p2] = ((unsigned)(d & 63) << 26) | (unsigned)s;
    }
}

// ---------------- K5: fine sort within bucket (LDS) + node offsets ----------------
__global__ __launch_bounds__(256) void k_fine(const unsigned* __restrict__ C,
                                              const int* __restrict__ bbase,
                                              unsigned short* __restrict__ FS,
                                              unsigned short* __restrict__ FD,
                                              int* __restrict__ offs_src,
                                              int* __restrict__ offs_dst,
                                              int E, int N, int NBK)
{
    __shared__ unsigned pay[FCAP];
    __shared__ unsigned short srt[FCAP];
    __shared__ int cnt[64], loffs[64], rnk[64];
    int i = blockIdx.x, t = threadIdx.x;
    int side = (i >= NBK) ? 1 : 0;
    int k = i - side * NBK;
    int start = bbase[i], end = bbase[i + 1];
    int count = end - start;
    int rel = start - side * E;
    unsigned short* out = side ? FD : FS;
    int* offs = side ? offs_dst : offs_src;
    if (t < 64) { cnt[t] = 0; rnk[t] = 0; }
    __syncthreads();

    if (count <= FCAP) {
        for (int p = t; p < count; p += 256) {
            unsigned v = C[start + p];
            pay[p] = v;
            atomicAdd(&cnt[v >> 26], 1);
        }
        __syncthreads();
        if (t < 64) {
            int v = cnt[t], inc = v;
#pragma unroll
            for (int m = 1; m < 64; m <<= 1) {
                int u = __shfl_up(inc, m, 64);
                if (t >= m) inc += u;
            }
            loffs[t] = inc - v;
        }
        __syncthreads();
        if (t < 64) {
            int node = k * 64 + t;
            if (node <= N) offs[node] = rel + loffs[t];
        }
        for (int p = t; p < count; p += 256) {
            unsigned v = pay[p];
            int n6 = v >> 26;
            int r = atomicAdd(&rnk[n6], 1);
            srt[loffs[n6] + r] = (unsigned short)(v & 0xFFFFu);
        }
        __syncthreads();
        for (int p = t; p < count; p += 256) out[rel + p] = srt[p];
    } else {
        for (int p = t; p < count; p += 256) atomicAdd(&cnt[C[start + p] >> 26], 1);
        __syncthreads();
        if (t < 64) {
            int v = cnt[t], inc = v;
#pragma unroll
            for (int m = 1; m < 64; m <<= 1) {
                int u = __shfl_up(inc, m, 64);
                if (t >= m) inc += u;
            }
            loffs[t] = inc - v;
        }
        __syncthreads();
        if (t < 64) {
            int node = k * 64 + t;
            if (node <= N) offs[node] = rel + loffs[t];
        }
        for (int p = t; p < count; p += 256) {
            unsigned v = C[start + p];
            int n6 = v >> 26;
            int r = atomicAdd(&rnk[n6], 1);
            out[rel + loffs[n6] + r] = (unsigned short)(v & 0xFFFFu);
        }
    }
}

// ---------------- K6: dst-side softmax denominator -> sv = 1/sum(exp(a)) ----------------
// no max subtraction: logits are O(+-5), exp is safe in fp32
__global__ __launch_bounds__(256) void k_softmax(const unsigned short* __restrict__ FD,
                                                 const int* __restrict__ offs_dst,
                                                 const float* __restrict__ el,
                                                 const float* __restrict__ er,
                                                 float* __restrict__ sv, int N)
{
    int wave = threadIdx.x >> 6;
    int lane = threadIdx.x & 63;
    int node = blockIdx.x * 4 + wave;
    if (node >= N) return;
    int start = offs_dst[node], end = offs_dst[node + 1];
    int h = lane & 3, q = lane >> 2;
    float er_h = er[node * 4 + h];
    float s = 0.f;
    for (int j = start + q; j < end; j += 16) {
        int src = FD[j];
        float a = el[src * 4 + h] + er_h;
        a = fmaxf(a, 0.01f * a);
        s += __expf(a);
    }
#pragma unroll
    for (int mask = 4; mask <= 32; mask <<= 1)
        s += __shfl_xor(s, mask, 64);
    if (lane < 4)
        sv[node * 4 + lane] = (s > 0.f) ? 1.0f / s : 0.f;
}

// ---------------- K7: src-side gather; att recomputed; bf16 Zp ----------------
// lane holds cols {2*lane, 2*lane+1}; heads h0=2*(lane&1)... pattern: h0=(2l)&3, h1=h0+1
__global__ __launch_bounds__(256) void k_gather(const unsigned short* __restrict__ FS,
                                                const int* __restrict__ offs_src,
                                                const float* __restrict__ el,
                                                const float* __restrict__ er,
                                                const float* __restrict__ sv,
                                                const unsigned short* __restrict__ Zp16,
                                                float* __restrict__ out, int N)
{
    int wave = threadIdx.x >> 6;
    int lane = threadIdx.x & 63;
    int node = blockIdx.x * 4 + wave;
    if (node >= N) return;
    int start = offs_src[node], end = offs_src[node + 1];
    bool sel = (lane & 1) != 0;       // heads (2,3) vs (0,1)
    float4 el4 = *(const float4*)(el + (size_t)node * 4);
    float el0 = sel ? el4.z : el4.x;
    float el1 = sel ? el4.w : el4.y;
    float acc0 = 0.f, acc1 = 0.f;
    int j = start;
    for (; j + 3 < end; j += 4) {
        int dd[4]; unsigned zz[4]; float4 e4[4], s4[4];
#pragma unroll
        for (int u = 0; u < 4; u++) {
            int d = __builtin_amdgcn_readfirstlane((int)FS[j + u]);
            dd[u] = d;
            e4[u] = *(const float4*)(er + (size_t)d * 4);
            s4[u] = *(const float4*)(sv + (size_t)d * 4);
            zz[u] = *(const unsigned*)(Zp16 + (size_t)d * CH + 2 * lane);
        }
#pragma unroll
        for (int u = 0; u < 4; u++) {
            float a0 = el0 + (sel ? e4[u].z : e4[u].x);
            float a1 = el1 + (sel ? e4[u].w : e4[u].y);
            a0 = fmaxf(a0, 0.01f * a0);
            a1 = fmaxf(a1, 0.01f * a1);
            float t0 = __expf(a0) * (sel ? s4[u].z : s4[u].x);
            float t1 = __expf(a1) * (sel ? s4[u].w : s4[u].y);
            acc0 = fmaf(t0, __uint_as_float(zz[u] << 16), acc0);
            acc1 = fmaf(t1, __uint_as_float(zz[u] & 0xffff0000u), acc1);
        }
    }
    for (; j < end; j++) {
        int d = __builtin_amdgcn_readfirstlane((int)FS[j]);
        float4 e4 = *(const float4*)(er + (size_t)d * 4);
        float4 s4 = *(const float4*)(sv + (size_t)d * 4);
        unsigned zz = *(const unsigned*)(Zp16 + (size_t)d * CH + 2 * lane);
        float a0 = el0 + (sel ? e4.z : e4.x);
        float a1 = el1 + (sel ? e4.w : e4.y);
        a0 = fmaxf(a0, 0.01f * a0);
        a1 = fmaxf(a1, 0.01f * a1);
        float t0 = __expf(a0) * (sel ? s4.z : s4.x);
        float t1 = __expf(a1) * (sel ? s4.w : s4.y);
        acc0 = fmaf(t0, __uint_as_float(zz << 16), acc0);
        acc1 = fmaf(t1, __uint_as_float(zz & 0xffff0000u), acc1);
    }
    float2 res; res.x = acc0; res.y = acc1;
    *(float2*)(out + (size_t)node * CH + 2 * lane) = res;
}

static inline char* align16(char* p) {
    return (char*)(((uintptr_t)p + 15) & ~(uintptr_t)15);
}

extern "C" void kernel_launch(void* const* d_in, const int* in_sizes, int n_in,
                              void* d_out, int out_size, void* d_ws, size_t ws_size,
                              hipStream_t stream)
{
    const int*   idx = (const int*)d_in[0];
    const float* Z   = (const float*)d_in[2];
    const float* W   = (const float*)d_in[3];
    const float* b   = (const float*)d_in[4];
    const float* al  = (const float*)d_in[5];
    const float* ar  = (const float*)d_in[6];
    float* out = (float*)d_out;

    const int E = in_sizes[0] / 2;
    const int N = in_sizes[2] / KIN;
    const int NBK = (N + 63) >> 6;      // 64-node buckets

    char* p = (char*)d_ws;
    unsigned short* Zp16 = (unsigned short*)p;  p = align16(p + sizeof(unsigned short) * (size_t)N * CH);
    float* el = (float*)p;               p = align16(p + sizeof(float) * (size_t)N * 4);
    float* er = (float*)p;               p = align16(p + sizeof(float) * (size_t)N * 4);
    float* sv = (float*)p;               p = align16(p + sizeof(float) * (size_t)N * 4);
    int* H    = (int*)p;                 p = align16(p + sizeof(int) * (size_t)2 * NBK * BH);
    int* btot = (int*)p;                 p = align16(p + sizeof(int) * (size_t)2 * NBK);
    int* bbase = (int*)p;                p = align16(p + sizeof(int) * ((size_t)2 * NBK + 1));
    unsigned* C = (unsigned*)p;          p = align16(p + sizeof(unsigned) * (size_t)2 * E);
    unsigned short* FS = (unsigned short*)p;  p = align16(p + sizeof(unsigned short) * (size_t)E);
    unsigned short* FD = (unsigned short*)p;  p = align16(p + sizeof(unsigned short) * (size_t)E);
    int* offs_src = (int*)p;             p = align16(p + sizeof(int) * ((size_t)N + 1));
    int* offs_dst = (int*)p;             p = align16(p + sizeof(int) * ((size_t)N + 1));

    hipMemsetAsync(btot, 0, sizeof(int) * (size_t)2 * NBK, stream);

    k_gemm  <<<(N + 31) / 32, 128, 0, stream>>>(Z, W, b, Zp16, N);
    k_logits<<<(N + 3) / 4,   256, 0, stream>>>(Zp16, al, ar, el, er, N);
    k_hist  <<<BH, 256, 0, stream>>>(idx, H, btot, E, NBK);
    k_scan  <<<1, 1024, 0, stream>>>(btot, bbase, 2 * NBK);
    k_bbase <<<2 * NBK, 128, 0, stream>>>(H, bbase);
    k_coarse<<<BH, 256, 0, stream>>>(idx, H, C, E, NBK);
    k_fine  <<<2 * NBK, 256, 0, stream>>>(C, bbase, FS, FD, offs_src, offs_dst, E, N, NBK);
    k_softmax<<<(N + 3) / 4, 256, 0, stream>>>(FD, offs_dst, el, er, sv, N);
    k_gather <<<(N + 3) / 4, 256, 0, stream>>>(FS, offs_src, el, er, sv, Zp16, out, N);
}

// Round 5
// 318.656 us; speedup vs baseline: 2.0080x; 2.0080x over previous
//
#include <hip/hip_runtime.h>
#include <hip/hip_bf16.h>
#include <math.h>

#define CH 128      // OUT_SIZE * HEADS
#define KIN 128     // IN_SIZE
#define BH 128      // histogram / coarse-scatter block count
#define FCAP 4096   // max edges per 64-node bucket handled in LDS (mean 2046, sd 45)

__device__ __forceinline__ unsigned short f2bf(float x) {
    __hip_bfloat16 h = __float2bfloat16(x);
    return *reinterpret_cast<unsigned short*>(&h);
}

// ---------------- K1: Zp16 = bf16(Z @ W^T + b)  -> [N, 128] ----------------
__global__ __launch_bounds__(128) void k_gemm(const float* __restrict__ Z,
                                              const float* __restrict__ W,
                                              const float* __restrict__ b,
                                              unsigned short* __restrict__ Zp16, int N)
{
    __shared__ float lZ[32][36];
    __shared__ float lW[32][132];
    const int tid = threadIdx.x;
    const int c_t = tid & 15;
    const int n_t = tid >> 4;
    const int c0 = c_t * 8;
    const int nb0 = blockIdx.x * 32;

    float4 accA[4], accB[4];
    const float4 bA = *(const float4*)(b + c0);
    const float4 bB = *(const float4*)(b + c0 + 4);
#pragma unroll
    for (int n = 0; n < 4; n++) { accA[n] = bA; accB[n] = bB; }

    for (int k0 = 0; k0 < KIN; k0 += 32) {
#pragma unroll
        for (int r = 0; r < 2; r++) {
            int idx = tid + r * 128;
            int n   = idx >> 3;
            int kk  = (idx & 7) * 4;
            int gn  = nb0 + n; if (gn >= N) gn = N - 1;
            float4 v = *(const float4*)(Z + (size_t)gn * KIN + k0 + kk);
            *(float4*)(&lZ[n][kk]) = v;
        }
#pragma unroll
        for (int r = 0; r < 8; r++) {
            int idx = tid + r * 128;
            int c   = idx >> 3;
            int kk  = (idx & 7) * 4;
            float4 v = *(const float4*)(W + (size_t)c * KIN + k0 + kk);
            lW[kk + 0][c] = v.x; lW[kk + 1][c] = v.y;
            lW[kk + 2][c] = v.z; lW[kk + 3][c] = v.w;
        }
        __syncthreads();
#pragma unroll
        for (int kk = 0; kk < 32; kk += 4) {
            float4 z[4];
#pragma unroll
            for (int n = 0; n < 4; n++) z[n] = *(float4*)(&lZ[n_t * 4 + n][kk]);
#pragma unroll
            for (int j = 0; j < 4; j++) {
                float4 wa = *(float4*)(&lW[kk + j][c0]);
                float4 wb = *(float4*)(&lW[kk + j][c0 + 4]);
#pragma unroll
                for (int n = 0; n < 4; n++) {
                    float zs = (j == 0) ? z[n].x : (j == 1) ? z[n].y : (j == 2) ? z[n].z : z[n].w;
                    accA[n].x += zs * wa.x; accA[n].y += zs * wa.y;
                    accA[n].z += zs * wa.z; accA[n].w += zs * wa.w;
                    accB[n].x += zs * wb.x; accB[n].y += zs * wb.y;
                    accB[n].z += zs * wb.z; accB[n].w += zs * wb.w;
                }
            }
        }
        __syncthreads();
    }
#pragma unroll
    for (int n = 0; n < 4; n++) {
        int gn = nb0 + n_t * 4 + n;
        if (gn < N) {
            union { unsigned short us[8]; uint4 v; } pk;
            pk.us[0] = f2bf(accA[n].x); pk.us[1] = f2bf(accA[n].y);
            pk.us[2] = f2bf(accA[n].z); pk.us[3] = f2bf(accA[n].w);
            pk.us[4] = f2bf(accB[n].x); pk.us[5] = f2bf(accB[n].y);
            pk.us[6] = f2bf(accB[n].z); pk.us[7] = f2bf(accB[n].w);
            *(uint4*)(Zp16 + (size_t)gn * CH + c0) = pk.v;
        }
    }
}

// ---------------- K1b: per-node attention logits (reads bf16 Zp) ----------------
__global__ __launch_bounds__(256) void k_logits(const unsigned short* __restrict__ Zp16,
                                                const float* __restrict__ al,
                                                const float* __restrict__ ar,
                                                float* __restrict__ el,
                                                float* __restrict__ er, int N)
{
    int wave = threadIdx.x >> 6;
    int lane = threadIdx.x & 63;
    int node = blockIdx.x * 4 + wave;
    if (node >= N) return;
    float z1 = __uint_as_float((unsigned)Zp16[(size_t)node * CH + lane] << 16);
    float z2 = __uint_as_float((unsigned)Zp16[(size_t)node * CH + 64 + lane] << 16);
    float vl = z1 * al[lane] + z2 * al[64 + lane];
    float vr = z1 * ar[lane] + z2 * ar[64 + lane];
#pragma unroll
    for (int m = 4; m <= 32; m <<= 1) {
        vl += __shfl_xor(vl, m, 64);
        vr += __shfl_xor(vr, m, 64);
    }
    if (lane < 4) {
        el[node * 4 + lane] = vl;
        er[node * 4 + lane] = vr;
    }
}

// ---------------- K2: per-block bucket histograms + bucket totals ----------------
__global__ __launch_bounds__(256) void k_hist(const int* __restrict__ idx,
                                              int* __restrict__ H,
                                              int* __restrict__ btot, int E, int NBK)
{
    __shared__ int lc[2 * 1024];
    int b = blockIdx.x, t = threadIdx.x;
    for (int i = t; i < 2 * NBK; i += 256) lc[i] = 0;
    __syncthreads();
    int chunk = (E + BH - 1) / BH;
    int lo = b * chunk, hi = min(lo + chunk, E);
    for (int e = lo + t; e < hi; e += 256) {
        int s = idx[e], d = idx[E + e];
        atomicAdd(&lc[s >> 6], 1);
        atomicAdd(&lc[NBK + (d >> 6)], 1);
    }
    __syncthreads();
    for (int i = t; i < 2 * NBK; i += 256) {
        int v = lc[i];
        H[(size_t)i * BH + b] = v;
        if (v) atomicAdd(&btot[i], v);
    }
}

// ---------------- K3b: single-block exclusive scan ----------------
__global__ __launch_bounds__(1024) void k_scan(const int* __restrict__ deg,
                                               int* __restrict__ offs, int n)
{
    __shared__ int part[1024];
    int t = threadIdx.x;
    int chunk = (n + 1023) >> 10;
    int lo = t * chunk;
    int hi = min(lo + chunk, n);
    int s = 0;
    for (int i = lo; i < hi; i++) s += deg[i];
    part[t] = s;
    __syncthreads();
    for (int off = 1; off < 1024; off <<= 1) {
        int v = (t >= off) ? part[t - off] : 0;
        __syncthreads();
        part[t] += v;
        __syncthreads();
    }
    int run = (t == 0) ? 0 : part[t - 1];
    for (int i = lo; i < hi; i++) { offs[i] = run; run += deg[i]; }
    if (t == 1023) offs[n] = part[1023];
}

// ---------------- K3c: per-bucket block bases ----------------
__global__ __launch_bounds__(128) void k_bbase(int* __restrict__ H,
                                               const int* __restrict__ bbase)
{
    int i = blockIdx.x, t = threadIdx.x;
    int v = H[(size_t)i * BH + t];
    __shared__ int part[128];
    part[t] = v;
    __syncthreads();
    for (int off = 1; off < 128; off <<= 1) {
        int u = (t >= off) ? part[t - off] : 0;
        __syncthreads();
        part[t] += u;
        __syncthreads();
    }
    H[(size_t)i * BH + t] = (t == 0 ? 0 : part[t - 1]) + bbase[i];
}

// ---------------- K4: coarse scatter into bucket-sorted array ----------------
__global__ __launch_bounds__(256) void k_coarse(const int* __restrict__ idx,
                                                const int* __restrict__ H,
                                                unsigned* __restrict__ C,
                                                int E, int NBK)
{
    __shared__ int lc[2 * 1024];
    int b = blockIdx.x, t = threadIdx.x;
    for (int i = t; i < 2 * NBK; i += 256) lc[i] = H[(size_t)i * BH + b];
    __syncthreads();
    int chunk = (E + BH - 1) / BH;
    int lo = b * chunk, hi = min(lo + chunk, E);
    for (int e = lo + t; e < hi; e += 256) {
        int s = idx[e], d = idx[E + e];
        int p = atomicAdd(&lc[s >> 6], 1);
        C[p] = ((unsigned)(s & 63) << 26) | (unsigned)d;
        int p2 = atomicAdd(&lc[NBK + (d >> 6)], 1);
        C[p2] = ((unsigned)(d & 63) << 26) | (unsigned)s;
    }
}

// ---------------- K5: fine sort within bucket (LDS) + node offsets ----------------
__global__ __launch_bounds__(256) void k_fine(const unsigned* __restrict__ C,
                                              const int* __restrict__ bbase,
                                              unsigned short* __restrict__ FS,
                                              unsigned short* __restrict__ FD,
                                              int* __restrict__ offs_src,
                                              int* __restrict__ offs_dst,
                                              int E, int N, int NBK)
{
    __shared__ unsigned pay[FCAP];
    __shared__ unsigned short srt[FCAP];
    __shared__ int cnt[64], loffs[64], rnk[64];
    int i = blockIdx.x, t = threadIdx.x;
    int side = (i >= NBK) ? 1 : 0;
    int k = i - side * NBK;
    int start = bbase[i], end = bbase[i + 1];
    int count = end - start;
    int rel = start - side * E;
    unsigned short* out = side ? FD : FS;
    int* offs = side ? offs_dst : offs_src;
    if (t < 64) { cnt[t] = 0; rnk[t] = 0; }
    __syncthreads();

    if (count <= FCAP) {
        for (int p = t; p < count; p += 256) {
            unsigned v = C[start + p];
            pay[p] = v;
            atomicAdd(&cnt[v >> 26], 1);
        }
        __syncthreads();
        if (t < 64) {
            int v = cnt[t], inc = v;
#pragma unroll
            for (int m = 1; m < 64; m <<= 1) {
                int u = __shfl_up(inc, m, 64);
                if (t >= m) inc += u;
            }
            loffs[t] = inc - v;
        }
        __syncthreads();
        if (t < 64) {
            int node = k * 64 + t;
            if (node <= N) offs[node] = rel + loffs[t];
        }
        for (int p = t; p < count; p += 256) {
            unsigned v = pay[p];
            int n6 = v >> 26;
            int r = atomicAdd(&rnk[n6], 1);
            srt[loffs[n6] + r] = (unsigned short)(v & 0xFFFFu);
        }
        __syncthreads();
        for (int p = t; p < count; p += 256) out[rel + p] = srt[p];
    } else {
        for (int p = t; p < count; p += 256) atomicAdd(&cnt[C[start + p] >> 26], 1);
        __syncthreads();
        if (t < 64) {
            int v = cnt[t], inc = v;
#pragma unroll
            for (int m = 1; m < 64; m <<= 1) {
                int u = __shfl_up(inc, m, 64);
                if (t >= m) inc += u;
            }
            loffs[t] = inc - v;
        }
        __syncthreads();
        if (t < 64) {
            int node = k * 64 + t;
            if (node <= N) offs[node] = rel + loffs[t];
        }
        for (int p = t; p < count; p += 256) {
            unsigned v = C[start + p];
            int n6 = v >> 26;
            int r = atomicAdd(&rnk[n6], 1);
            out[rel + loffs[n6] + r] = (unsigned short)(v & 0xFFFFu);
        }
    }
}

// ---------------- K6: dst-side softmax denom; writes interleaved esv ----------------
// esv[node*8 + 2h] = er_h ; esv[node*8 + 2h + 1] = 1/sum_h
__global__ __launch_bounds__(256) void k_softmax(const unsigned short* __restrict__ FD,
                                                 const int* __restrict__ offs_dst,
                                                 const float* __restrict__ el,
                                                 const float* __restrict__ er,
                                                 float* __restrict__ esv, int N)
{
    int wave = threadIdx.x >> 6;
    int lane = threadIdx.x & 63;
    int node = blockIdx.x * 4 + wave;
    if (node >= N) return;
    int start = offs_dst[node], end = offs_dst[node + 1];
    int h = lane & 3, q = lane >> 2;
    float er_h = er[node * 4 + h];
    float s = 0.f;
    for (int j = start + q; j < end; j += 16) {
        int src = FD[j];
        float a = el[src * 4 + h] + er_h;
        a = fmaxf(a, 0.01f * a);
        s += __expf(a);
    }
#pragma unroll
    for (int mask = 4; mask <= 32; mask <<= 1)
        s += __shfl_xor(s, mask, 64);
    if (lane < 4) {
        esv[(size_t)node * 8 + 2 * lane]     = er_h;
        esv[(size_t)node * 8 + 2 * lane + 1] = (s > 0.f) ? 1.0f / s : 0.f;
    }
}

// ---------------- K7: src-side gather; att recomputed; bf16 Zp ----------------
// lane holds cols {2*lane, 2*lane+1}; heads h0=2*(lane&1), h1=h0+1
__global__ __launch_bounds__(256) void k_gather(const unsigned short* __restrict__ FS,
                                                const int* __restrict__ offs_src,
                                                const float* __restrict__ el,
                                                const float* __restrict__ esv,
                                                const unsigned short* __restrict__ Zp16,
                                                float* __restrict__ out, int N)
{
    int wave = threadIdx.x >> 6;
    int lane = threadIdx.x & 63;
    int node = blockIdx.x * 4 + wave;
    if (node >= N) return;
    int start = offs_src[node], end = offs_src[node + 1];
    int h0 = (lane & 1) * 2;
    float2 elp = *(const float2*)(el + (size_t)node * 4 + h0);
    float acc0 = 0.f, acc1 = 0.f;
    int j = start;
    for (; j + 1 < end; j += 2) {
        int d0 = FS[j], d1 = FS[j + 1];
        float4 ev0 = *(const float4*)(esv + (size_t)d0 * 8 + 2 * h0);
        float4 ev1 = *(const float4*)(esv + (size_t)d1 * 8 + 2 * h0);
        unsigned z0 = *(const unsigned*)(Zp16 + (size_t)d0 * CH + 2 * lane);
        unsigned z1 = *(const unsigned*)(Zp16 + (size_t)d1 * CH + 2 * lane);
        float a00 = elp.x + ev0.x, a01 = elp.y + ev0.z;
        float a10 = elp.x + ev1.x, a11 = elp.y + ev1.z;
        a00 = fmaxf(a00, 0.01f * a00); a01 = fmaxf(a01, 0.01f * a01);
        a10 = fmaxf(a10, 0.01f * a10); a11 = fmaxf(a11, 0.01f * a11);
        float t00 = __expf(a00) * ev0.y, t01 = __expf(a01) * ev0.w;
        float t10 = __expf(a10) * ev1.y, t11 = __expf(a11) * ev1.w;
        acc0 = fmaf(t00, __uint_as_float(z0 << 16), acc0);
        acc1 = fmaf(t01, __uint_as_float(z0 & 0xffff0000u), acc1);
        acc0 = fmaf(t10, __uint_as_float(z1 << 16), acc0);
        acc1 = fmaf(t11, __uint_as_float(z1 & 0xffff0000u), acc1);
    }
    if (j < end) {
        int d0 = FS[j];
        float4 ev0 = *(const float4*)(esv + (size_t)d0 * 8 + 2 * h0);
        unsigned z0 = *(const unsigned*)(Zp16 + (size_t)d0 * CH + 2 * lane);
        float a00 = elp.x + ev0.x, a01 = elp.y + ev0.z;
        a00 = fmaxf(a00, 0.01f * a00); a01 = fmaxf(a01, 0.01f * a01);
        float t00 = __expf(a00) * ev0.y, t01 = __expf(a01) * ev0.w;
        acc0 = fmaf(t00, __uint_as_float(z0 << 16), acc0);
        acc1 = fmaf(t01, __uint_as_float(z0 & 0xffff0000u), acc1);
    }
    float2 res; res.x = acc0; res.y = acc1;
    *(float2*)(out + (size_t)node * CH + 2 * lane) = res;
}

static inline char* align16(char* p) {
    return (char*)(((uintptr_t)p + 15) & ~(uintptr_t)15);
}

extern "C" void kernel_launch(void* const* d_in, const int* in_sizes, int n_in,
                              void* d_out, int out_size, void* d_ws, size_t ws_size,
                              hipStream_t stream)
{
    const int*   idx = (const int*)d_in[0];
    const float* Z   = (const float*)d_in[2];
    const float* W   = (const float*)d_in[3];
    const float* b   = (const float*)d_in[4];
    const float* al  = (const float*)d_in[5];
    const float* ar  = (const float*)d_in[6];
    float* out = (float*)d_out;

    const int E = in_sizes[0] / 2;
    const int N = in_sizes[2] / KIN;
    const int NBK = (N + 63) >> 6;      // 64-node buckets

    char* p = (char*)d_ws;
    unsigned short* Zp16 = (unsigned short*)p;  p = align16(p + sizeof(unsigned short) * (size_t)N * CH);
    float* el  = (float*)p;              p = align16(p + sizeof(float) * (size_t)N * 4);
    float* er  = (float*)p;              p = align16(p + sizeof(float) * (size_t)N * 4);
    float* esv = (float*)p;              p = align16(p + sizeof(float) * (size_t)N * 8);
    int* H    = (int*)p;                 p = align16(p + sizeof(int) * (size_t)2 * NBK * BH);
    int* btot = (int*)p;                 p = align16(p + sizeof(int) * (size_t)2 * NBK);
    int* bbase = (int*)p;                p = align16(p + sizeof(int) * ((size_t)2 * NBK + 1));
    unsigned* C = (unsigned*)p;          p = align16(p + sizeof(unsigned) * (size_t)2 * E);
    unsigned short* FS = (unsigned short*)p;  p = align16(p + sizeof(unsigned short) * (size_t)E);
    unsigned short* FD = (unsigned short*)p;  p = align16(p + sizeof(unsigned short) * (size_t)E);
    int* offs_src = (int*)p;             p = align16(p + sizeof(int) * ((size_t)N + 1));
    int* offs_dst = (int*)p;             p = align16(p + sizeof(int) * ((size_t)N + 1));

    hipMemsetAsync(btot, 0, sizeof(int) * (size_t)2 * NBK, stream);

    k_gemm  <<<(N + 31) / 32, 128, 0, stream>>>(Z, W, b, Zp16, N);
    k_logits<<<(N + 3) / 4,   256, 0, stream>>>(Zp16, al, ar, el, er, N);
    k_hist  <<<BH, 256, 0, stream>>>(idx, H, btot, E, NBK);
    k_scan  <<<1, 1024, 0, stream>>>(btot, bbase, 2 * NBK);
    k_bbase <<<2 * NBK, 128, 0, stream>>>(H, bbase);
    k_coarse<<<BH, 256, 0, stream>>>(idx, H, C, E, NBK);
    k_fine  <<<2 * NBK, 256, 0, stream>>>(C, bbase, FS, FD, offs_src, offs_dst, E, N, NBK);
    k_softmax<<<(N + 3) / 4, 256, 0, stream>>>(FD, offs_dst, el, er, esv, N);
    k_gather <<<(N + 3) / 4, 256, 0, stream>>>(FS, offs_src, el, esv, Zp16, out, N);
}

// Round 6
// 281.592 us; speedup vs baseline: 2.2723x; 1.1316x over previous
//
#include <hip/hip_runtime.h>
#include <hip/hip_bf16.h>
#include <math.h>

#define CH 128      // OUT_SIZE * HEADS
#define KIN 128     // IN_SIZE
#define BH 128      // histogram / coarse-scatter block count
#define FCAP 4096   // max edges per 64-node bucket handled in LDS (mean 2046, sd 45)

__device__ __forceinline__ unsigned short f2bf(float x) {
    __hip_bfloat16 h = __float2bfloat16(x);
    return *reinterpret_cast<unsigned short*>(&h);
}

// ------- K1: Zp16 = bf16(Z @ W^T + b); fused el/er logits epilogue -------
__global__ __launch_bounds__(128) void k_gemm(const float* __restrict__ Z,
                                              const float* __restrict__ W,
                                              const float* __restrict__ b,
                                              const float* __restrict__ al,
                                              const float* __restrict__ ar,
                                              unsigned short* __restrict__ Zp16,
                                              float* __restrict__ el,
                                              float* __restrict__ er, int N)
{
    __shared__ float lZ[32][36];
    __shared__ float lW[32][132];
    const int tid = threadIdx.x;
    const int c_t = tid & 15;
    const int n_t = tid >> 4;
    const int c0 = c_t * 8;
    const int nb0 = blockIdx.x * 32;

    float4 accA[4], accB[4];
    const float4 bA = *(const float4*)(b + c0);
    const float4 bB = *(const float4*)(b + c0 + 4);
#pragma unroll
    for (int n = 0; n < 4; n++) { accA[n] = bA; accB[n] = bB; }

    for (int k0 = 0; k0 < KIN; k0 += 32) {
#pragma unroll
        for (int r = 0; r < 2; r++) {
            int idx = tid + r * 128;
            int n   = idx >> 3;
            int kk  = (idx & 7) * 4;
            int gn  = nb0 + n; if (gn >= N) gn = N - 1;
            float4 v = *(const float4*)(Z + (size_t)gn * KIN + k0 + kk);
            *(float4*)(&lZ[n][kk]) = v;
        }
#pragma unroll
        for (int r = 0; r < 8; r++) {
            int idx = tid + r * 128;
            int c   = idx >> 3;
            int kk  = (idx & 7) * 4;
            float4 v = *(const float4*)(W + (size_t)c * KIN + k0 + kk);
            lW[kk + 0][c] = v.x; lW[kk + 1][c] = v.y;
            lW[kk + 2][c] = v.z; lW[kk + 3][c] = v.w;
        }
        __syncthreads();
#pragma unroll
        for (int kk = 0; kk < 32; kk += 4) {
            float4 z[4];
#pragma unroll
            for (int n = 0; n < 4; n++) z[n] = *(float4*)(&lZ[n_t * 4 + n][kk]);
#pragma unroll
            for (int j = 0; j < 4; j++) {
                float4 wa = *(float4*)(&lW[kk + j][c0]);
                float4 wb = *(float4*)(&lW[kk + j][c0 + 4]);
#pragma unroll
                for (int n = 0; n < 4; n++) {
                    float zs = (j == 0) ? z[n].x : (j == 1) ? z[n].y : (j == 2) ? z[n].z : z[n].w;
                    accA[n].x += zs * wa.x; accA[n].y += zs * wa.y;
                    accA[n].z += zs * wa.z; accA[n].w += zs * wa.w;
                    accB[n].x += zs * wb.x; accB[n].y += zs * wb.y;
                    accB[n].z += zs * wb.z; accB[n].w += zs * wb.w;
                }
            }
        }
        __syncthreads();
    }

    const float4 alA = *(const float4*)(al + c0);
    const float4 alB = *(const float4*)(al + c0 + 4);
    const float4 arA = *(const float4*)(ar + c0);
    const float4 arB = *(const float4*)(ar + c0 + 4);

#pragma unroll
    for (int n = 0; n < 4; n++) {
        int gn = nb0 + n_t * 4 + n;
        if (gn < N) {
            union { unsigned short us[8]; uint4 v; } pkv;
            pkv.us[0] = f2bf(accA[n].x); pkv.us[1] = f2bf(accA[n].y);
            pkv.us[2] = f2bf(accA[n].z); pkv.us[3] = f2bf(accA[n].w);
            pkv.us[4] = f2bf(accB[n].x); pkv.us[5] = f2bf(accB[n].y);
            pkv.us[6] = f2bf(accB[n].z); pkv.us[7] = f2bf(accB[n].w);
            *(uint4*)(Zp16 + (size_t)gn * CH + c0) = pkv.v;
        }
        // per-head logit partials: head h picks cols c0+h and c0+4+h
        float e0 = accA[n].x * alA.x + accB[n].x * alB.x;
        float e1 = accA[n].y * alA.y + accB[n].y * alB.y;
        float e2 = accA[n].z * alA.z + accB[n].z * alB.z;
        float e3 = accA[n].w * alA.w + accB[n].w * alB.w;
        float r0 = accA[n].x * arA.x + accB[n].x * arB.x;
        float r1 = accA[n].y * arA.y + accB[n].y * arB.y;
        float r2 = accA[n].z * arA.z + accB[n].z * arB.z;
        float r3 = accA[n].w * arA.w + accB[n].w * arB.w;
#pragma unroll
        for (int m = 1; m <= 8; m <<= 1) {
            e0 += __shfl_xor(e0, m, 64); e1 += __shfl_xor(e1, m, 64);
            e2 += __shfl_xor(e2, m, 64); e3 += __shfl_xor(e3, m, 64);
            r0 += __shfl_xor(r0, m, 64); r1 += __shfl_xor(r1, m, 64);
            r2 += __shfl_xor(r2, m, 64); r3 += __shfl_xor(r3, m, 64);
        }
        if (c_t == 0 && gn < N) {
            float4 ev; ev.x = e0; ev.y = e1; ev.z = e2; ev.w = e3;
            float4 rv; rv.x = r0; rv.y = r1; rv.z = r2; rv.w = r3;
            *(float4*)(el + (size_t)gn * 4) = ev;
            *(float4*)(er + (size_t)gn * 4) = rv;
        }
    }
}

// ---------------- K2: per-block bucket histograms + bucket totals ----------------
__global__ __launch_bounds__(256) void k_hist(const int* __restrict__ idx,
                                              int* __restrict__ H,
                                              int* __restrict__ btot, int E, int NBK)
{
    __shared__ int lc[2 * 1024];
    int b = blockIdx.x, t = threadIdx.x;
    for (int i = t; i < 2 * NBK; i += 256) lc[i] = 0;
    __syncthreads();
    int chunk = (E + BH - 1) / BH;
    int lo = b * chunk, hi = min(lo + chunk, E);
    for (int e = lo + t; e < hi; e += 256) {
        int s = idx[e], d = idx[E + e];
        atomicAdd(&lc[s >> 6], 1);
        atomicAdd(&lc[NBK + (d >> 6)], 1);
    }
    __syncthreads();
    for (int i = t; i < 2 * NBK; i += 256) {
        int v = lc[i];
        H[(size_t)i * BH + b] = v;
        if (v) atomicAdd(&btot[i], v);
    }
}

// ---------------- K3b: single-block exclusive scan ----------------
__global__ __launch_bounds__(1024) void k_scan(const int* __restrict__ deg,
                                               int* __restrict__ offs, int n)
{
    __shared__ int part[1024];
    int t = threadIdx.x;
    int chunk = (n + 1023) >> 10;
    int lo = t * chunk;
    int hi = min(lo + chunk, n);
    int s = 0;
    for (int i = lo; i < hi; i++) s += deg[i];
    part[t] = s;
    __syncthreads();
    for (int off = 1; off < 1024; off <<= 1) {
        int v = (t >= off) ? part[t - off] : 0;
        __syncthreads();
        part[t] += v;
        __syncthreads();
    }
    int run = (t == 0) ? 0 : part[t - 1];
    for (int i = lo; i < hi; i++) { offs[i] = run; run += deg[i]; }
    if (t == 1023) offs[n] = part[1023];
}

// ---------------- K3c: per-bucket block bases ----------------
__global__ __launch_bounds__(128) void k_bbase(int* __restrict__ H,
                                               const int* __restrict__ bbase)
{
    int i = blockIdx.x, t = threadIdx.x;
    int v = H[(size_t)i * BH + t];
    __shared__ int part[128];
    part[t] = v;
    __syncthreads();
    for (int off = 1; off < 128; off <<= 1) {
        int u = (t >= off) ? part[t - off] : 0;
        __syncthreads();
        part[t] += u;
        __syncthreads();
    }
    H[(size_t)i * BH + t] = (t == 0 ? 0 : part[t - 1]) + bbase[i];
}

// ---------------- K4: coarse scatter into bucket-sorted array ----------------
__global__ __launch_bounds__(256) void k_coarse(const int* __restrict__ idx,
                                                const int* __restrict__ H,
                                                unsigned* __restrict__ C,
                                                int E, int NBK)
{
    __shared__ int lc[2 * 1024];
    int b = blockIdx.x, t = threadIdx.x;
    for (int i = t; i < 2 * NBK; i += 256) lc[i] = H[(size_t)i * BH + b];
    __syncthreads();
    int chunk = (E + BH - 1) / BH;
    int lo = b * chunk, hi = min(lo + chunk, E);
    for (int e = lo + t; e < hi; e += 256) {
        int s = idx[e], d = idx[E + e];
        int p = atomicAdd(&lc[s >> 6], 1);
        C[p] = ((unsigned)(s & 63) << 26) | (unsigned)d;
        int p2 = atomicAdd(&lc[NBK + (d >> 6)], 1);
        C[p2] = ((unsigned)(d & 63) << 26) | (unsigned)s;
    }
}

// ---------------- K5: fine sort within bucket (LDS) + node offsets ----------------
__global__ __launch_bounds__(256) void k_fine(const unsigned* __restrict__ C,
                                              const int* __restrict__ bbase,
                                              unsigned short* __restrict__ FS,
                                              unsigned short* __restrict__ FD,
                                              int* __restrict__ offs_src,
                                              int* __restrict__ offs_dst,
                                              int E, int N, int NBK)
{
    __shared__ unsigned pay[FCAP];
    __shared__ unsigned short srt[FCAP];
    __shared__ int cnt[64], loffs[64], rnk[64];
    int i = blockIdx.x, t = threadIdx.x;
    int side = (i >= NBK) ? 1 : 0;
    int k = i - side * NBK;
    int start = bbase[i], end = bbase[i + 1];
    int count = end - start;
    int rel = start - side * E;
    unsigned short* out = side ? FD : FS;
    int* offs = side ? offs_dst : offs_src;
    if (t < 64) { cnt[t] = 0; rnk[t] = 0; }
    __syncthreads();

    if (count <= FCAP) {
        for (int p = t; p < count; p += 256) {
            unsigned v = C[start + p];
            pay[p] = v;
            atomicAdd(&cnt[v >> 26], 1);
        }
        __syncthreads();
        if (t < 64) {
            int v = cnt[t], inc = v;
#pragma unroll
            for (int m = 1; m < 64; m <<= 1) {
                int u = __shfl_up(inc, m, 64);
                if (t >= m) inc += u;
            }
            loffs[t] = inc - v;
        }
        __syncthreads();
        if (t < 64) {
            int node = k * 64 + t;
            if (node <= N) offs[node] = rel + loffs[t];
        }
        for (int p = t; p < count; p += 256) {
            unsigned v = pay[p];
            int n6 = v >> 26;
            int r = atomicAdd(&rnk[n6], 1);
            srt[loffs[n6] + r] = (unsigned short)(v & 0xFFFFu);
        }
        __syncthreads();
        for (int p = t; p < count; p += 256) out[rel + p] = srt[p];
    } else {
        for (int p = t; p < count; p += 256) atomicAdd(&cnt[C[start + p] >> 26], 1);
        __syncthreads();
        if (t < 64) {
            int v = cnt[t], inc = v;
#pragma unroll
            for (int m = 1; m < 64; m <<= 1) {
                int u = __shfl_up(inc, m, 64);
                if (t >= m) inc += u;
            }
            loffs[t] = inc - v;
        }
        __syncthreads();
        if (t < 64) {
            int node = k * 64 + t;
            if (node <= N) offs[node] = rel + loffs[t];
        }
        for (int p = t; p < count; p += 256) {
            unsigned v = C[start + p];
            int n6 = v >> 26;
            int r = atomicAdd(&rnk[n6], 1);
            out[rel + loffs[n6] + r] = (unsigned short)(v & 0xFFFFu);
        }
    }
}

// ---------------- K6: dst-side softmax denom; writes interleaved esv ----------------
// esv[node*8 + 2h] = er_h ; esv[node*8 + 2h + 1] = 1/sum_h
__global__ __launch_bounds__(256) void k_softmax(const unsigned short* __restrict__ FD,
                                                 const int* __restrict__ offs_dst,
                                                 const float* __restrict__ el,
                                                 const float* __restrict__ er,
                                                 float* __restrict__ esv, int N)
{
    int wave = threadIdx.x >> 6;
    int lane = threadIdx.x & 63;
    int node = blockIdx.x * 4 + wave;
    if (node >= N) return;
    int start = offs_dst[node], end = offs_dst[node + 1];
    int h = lane & 3, q = lane >> 2;
    float er_h = er[(size_t)node * 4 + h];
    float s = 0.f;
    for (int j = start + q; j < end; j += 16) {
        int src = FD[j];
        float a = el[(size_t)src * 4 + h] + er_h;
        a = fmaxf(a, 0.01f * a);
        s += __expf(a);
    }
#pragma unroll
    for (int mask = 4; mask <= 32; mask <<= 1)
        s += __shfl_xor(s, mask, 64);
    if (lane < 4) {
        esv[(size_t)node * 8 + 2 * lane]     = er_h;
        esv[(size_t)node * 8 + 2 * lane + 1] = (s > 0.f) ? 1.0f / s : 0.f;
    }
}

// ---------------- K7: src-side gather, de-duplicated att ----------------
// Phase A: lane (slot=lane>>1, pr=lane&1) computes att for heads {2pr, 2pr+1}
//          of edge (chunk,slot); packs as 2xbf16 in one dword (register).
// Phase B: per edge, broadcast d + att-pair via v_readlane (uniform index ->
//          SGPR, scalar-base Zp load). Lane covers cols {2*lane, 2*lane+1}.
__global__ __launch_bounds__(256) void k_gather(const unsigned short* __restrict__ FS,
                                                const int* __restrict__ offs_src,
                                                const float* __restrict__ el,
                                                const float* __restrict__ esv,
                                                const unsigned short* __restrict__ Zp16,
                                                float* __restrict__ out, int N)
{
    int wave = threadIdx.x >> 6;
    int lane = threadIdx.x & 63;
    int node = blockIdx.x * 4 + wave;
    if (node >= N) return;
    int start = offs_src[node], end = offs_src[node + 1];
    int slot = lane >> 1;
    int pr   = lane & 1;
    float2 elp = *(const float2*)(el + (size_t)node * 4 + 2 * pr);
    float acc0 = 0.f, acc1 = 0.f;

    for (int j0 = start; j0 < end; j0 += 32) {
        int ns = end - j0; if (ns > 32) ns = 32;
        int d = 0; unsigned pk = 0;
        if (slot < ns) {
            d = FS[j0 + slot];
            float4 es = *(const float4*)(esv + (size_t)d * 8 + 4 * pr); // er_h0,sv_h0,er_h1,sv_h1
            float a0 = elp.x + es.x;
            float a1 = elp.y + es.z;
            a0 = fmaxf(a0, 0.01f * a0);
            a1 = fmaxf(a1, 0.01f * a1);
            float t0 = __expf(a0) * es.y;
            float t1 = __expf(a1) * es.w;
            unsigned u0 = __float_as_uint(t0) + 0x8000u;   // round-to-nearest bf16
            unsigned u1 = __float_as_uint(t1) + 0x8000u;
            pk = (u0 >> 16) | (u1 & 0xffff0000u);
        }
        int u = 0;
        for (; u + 3 < ns; u += 4) {
            int b0 = 2 * u;
            int du0 = __builtin_amdgcn_readlane(d, b0);
            int du1 = __builtin_amdgcn_readlane(d, b0 + 2);
            int du2 = __builtin_amdgcn_readlane(d, b0 + 4);
            int du3 = __builtin_amdgcn_readlane(d, b0 + 6);
            unsigned p0a = (unsigned)__builtin_amdgcn_readlane((int)pk, b0);
            unsigned p0b = (unsigned)__builtin_amdgcn_readlane((int)pk, b0 + 1);
            unsigned p1a = (unsigned)__builtin_amdgcn_readlane((int)pk, b0 + 2);
            unsigned p1b = (unsigned)__builtin_amdgcn_readlane((int)pk, b0 + 3);
            unsigned p2a = (unsigned)__builtin_amdgcn_readlane((int)pk, b0 + 4);
            unsigned p2b = (unsigned)__builtin_amdgcn_readlane((int)pk, b0 + 5);
            unsigned p3a = (unsigned)__builtin_amdgcn_readlane((int)pk, b0 + 6);
            unsigned p3b = (unsigned)__builtin_amdgcn_readlane((int)pk, b0 + 7);
            unsigned z0 = *(const unsigned*)(Zp16 + (size_t)du0 * CH + 2 * lane);
            unsigned z1 = *(const unsigned*)(Zp16 + (size_t)du1 * CH + 2 * lane);
            unsigned z2 = *(const unsigned*)(Zp16 + (size_t)du2 * CH + 2 * lane);
            unsigned z3 = *(const unsigned*)(Zp16 + (size_t)du3 * CH + 2 * lane);
            unsigned q0 = pr ? p0b : p0a;
            unsigned q1 = pr ? p1b : p1a;
            unsigned q2 = pr ? p2b : p2a;
            unsigned q3 = pr ? p3b : p3a;
            acc0 = fmaf(__uint_as_float(q0 << 16), __uint_as_float(z0 << 16), acc0);
            acc1 = fmaf(__uint_as_float(q0 & 0xffff0000u), __uint_as_float(z0 & 0xffff0000u), acc1);
            acc0 = fmaf(__uint_as_float(q1 << 16), __uint_as_float(z1 << 16), acc0);
            acc1 = fmaf(__uint_as_float(q1 & 0xffff0000u), __uint_as_float(z1 & 0xffff0000u), acc1);
            acc0 = fmaf(__uint_as_float(q2 << 16), __uint_as_float(z2 << 16), acc0);
            acc1 = fmaf(__uint_as_float(q2 & 0xffff0000u), __uint_as_float(z2 & 0xffff0000u), acc1);
            acc0 = fmaf(__uint_as_float(q3 << 16), __uint_as_float(z3 << 16), acc0);
            acc1 = fmaf(__uint_as_float(q3 & 0xffff0000u), __uint_as_float(z3 & 0xffff0000u), acc1);
        }
        for (; u < ns; u++) {
            int b0 = 2 * u;
            int du = __builtin_amdgcn_readlane(d, b0);
            unsigned pa = (unsigned)__builtin_amdgcn_readlane((int)pk, b0);
            unsigned pb = (unsigned)__builtin_amdgcn_readlane((int)pk, b0 + 1);
            unsigned z = *(const unsigned*)(Zp16 + (size_t)du * CH + 2 * lane);
            unsigned q = pr ? pb : pa;
            acc0 = fmaf(__uint_as_float(q << 16), __uint_as_float(z << 16), acc0);
            acc1 = fmaf(__uint_as_float(q & 0xffff0000u), __uint_as_float(z & 0xffff0000u), acc1);
        }
    }
    float2 res; res.x = acc0; res.y = acc1;
    *(float2*)(out + (size_t)node * CH + 2 * lane) = res;
}

static inline char* align16(char* p) {
    return (char*)(((uintptr_t)p + 15) & ~(uintptr_t)15);
}

extern "C" void kernel_launch(void* const* d_in, const int* in_sizes, int n_in,
                              void* d_out, int out_size, void* d_ws, size_t ws_size,
                              hipStream_t stream)
{
    const int*   idx = (const int*)d_in[0];
    const float* Z   = (const float*)d_in[2];
    const float* W   = (const float*)d_in[3];
    const float* b   = (const float*)d_in[4];
    const float* al  = (const float*)d_in[5];
    const float* ar  = (const float*)d_in[6];
    float* out = (float*)d_out;

    const int E = in_sizes[0] / 2;
    const int N = in_sizes[2] / KIN;
    const int NBK = (N + 63) >> 6;      // 64-node buckets

    char* p = (char*)d_ws;
    unsigned short* Zp16 = (unsigned short*)p;  p = align16(p + sizeof(unsigned short) * (size_t)N * CH);
    float* el  = (float*)p;              p = align16(p + sizeof(float) * (size_t)N * 4);
    float* er  = (float*)p;              p = align16(p + sizeof(float) * (size_t)N * 4);
    float* esv = (float*)p;              p = align16(p + sizeof(float) * (size_t)N * 8);
    int* H    = (int*)p;                 p = align16(p + sizeof(int) * (size_t)2 * NBK * BH);
    int* btot = (int*)p;                 p = align16(p + sizeof(int) * (size_t)2 * NBK);
    int* bbase = (int*)p;                p = align16(p + sizeof(int) * ((size_t)2 * NBK + 1));
    unsigned* C = (unsigned*)p;          p = align16(p + sizeof(unsigned) * (size_t)2 * E);
    unsigned short* FS = (unsigned short*)p;  p = align16(p + sizeof(unsigned short) * (size_t)E);
    unsigned short* FD = (unsigned short*)p;  p = align16(p + sizeof(unsigned short) * (size_t)E);
    int* offs_src = (int*)p;             p = align16(p + sizeof(int) * ((size_t)N + 1));
    int* offs_dst = (int*)p;             p = align16(p + sizeof(int) * ((size_t)N + 1));

    hipMemsetAsync(btot, 0, sizeof(int) * (size_t)2 * NBK, stream);

    k_gemm  <<<(N + 31) / 32, 128, 0, stream>>>(Z, W, b, al, ar, Zp16, el, er, N);
    k_hist  <<<BH, 256, 0, stream>>>(idx, H, btot, E, NBK);
    k_scan  <<<1, 1024, 0, stream>>>(btot, bbase, 2 * NBK);
    k_bbase <<<2 * NBK, 128, 0, stream>>>(H, bbase);
    k_coarse<<<BH, 256, 0, stream>>>(idx, H, C, E, NBK);
    k_fine  <<<2 * NBK, 256, 0, stream>>>(C, bbase, FS, FD, offs_src, offs_dst, E, N, NBK);
    k_softmax<<<(N + 3) / 4, 256, 0, stream>>>(FD, offs_dst, el, er, esv, N);
    k_gather <<<(N + 3) / 4, 256, 0, stream>>>(FS, offs_src, el, esv, Zp16, out, N);
}